// Round 4
// baseline (52.785 us; speedup 1.0000x reference)
//
#include <hip/hip_runtime.h>
#include <math.h>

// Problem geometry (from reference setup_inputs): B=1024, N=8192.
constexpr int N_ELEM = 8192;
constexpr int TPB    = 512;                 // threads per block (8 waves)
constexpr int CHUNKS = N_ELEM / 4 / TPB;    // float4 chunks per thread = 4

// ---------------------------------------------------------------------------
// Fused kernel: per-batch raw-moment reduction + 3x3 Kabsch solve.
// Sums (16 per batch):
//   s0      = sum w
//   s1..s3  = sum w * src_i
//   s4..s6  = sum w * (src_i + rcs_i)           (= corres)
//   s7..s15 = sum w * src_i * corres_j          (3x3, row-major)
// Then thread 0: cov -> SVD (f32 Jacobi on H^T H) -> R, t.
//
// R4 experiment: manual 2-deep software pipeline on the chunk loop — prefetch
// chunk c+1's 7 float4 while accumulating chunk c. Costs ~28 extra VGPRs
// (expect ~96 total, 5 waves/SIMD instead of 8) but doubles per-wave loads
// in flight. If flat vs R3's 46.3 us -> memory-path ceiling, declare roofline.
//
// NOTE: plain __launch_bounds__(TPB) only. R2's (TPB,8) min-waves constraint
// forced VGPR=32 and spilled the accumulators to scratch (48.8 -> 115 us).
// ---------------------------------------------------------------------------
__global__ __launch_bounds__(TPB) void gw_fused_kernel(
    const float* __restrict__ src, const float* __restrict__ rcs,
    const float* __restrict__ wts, float* __restrict__ out, int B)
{
    const size_t b = blockIdx.x;
    const float4* w4 = (const float4*)(wts + b * (size_t)N_ELEM);
    const float4* x0 = (const float4*)(src + b * (size_t)(3 * N_ELEM));
    const float4* x1 = x0 + N_ELEM / 4;
    const float4* x2 = x0 + 2 * (N_ELEM / 4);
    const float4* r0 = (const float4*)(rcs + b * (size_t)(3 * N_ELEM));
    const float4* r1 = r0 + N_ELEM / 4;
    const float4* r2 = r0 + 2 * (N_ELEM / 4);

    float s[16];
#pragma unroll
    for (int k = 0; k < 16; ++k) s[k] = 0.f;

    // ---- 2-deep pipelined chunk loop ----
    int idx = threadIdx.x;
    float4 wv = w4[idx];
    float4 a0 = x0[idx], a1 = x1[idx], a2 = x2[idx];
    float4 b0 = r0[idx], b1 = r1[idx], b2 = r2[idx];

#pragma unroll
    for (int c = 0; c < CHUNKS; ++c) {
        // prefetch next chunk while current accumulates (compile-time guard)
        float4 nwv, na0, na1, na2, nb0, nb1, nb2;
        if (c + 1 < CHUNKS) {
            const int nidx = (c + 1) * TPB + threadIdx.x;
            nwv = w4[nidx];
            na0 = x0[nidx]; na1 = x1[nidx]; na2 = x2[nidx];
            nb0 = r0[nidx]; nb1 = r1[nidx]; nb2 = r2[nidx];
        }

        const float* wp = (const float*)&wv;
        const float* p0 = (const float*)&a0;
        const float* p1 = (const float*)&a1;
        const float* p2 = (const float*)&a2;
        const float* q0 = (const float*)&b0;
        const float* q1 = (const float*)&b1;
        const float* q2 = (const float*)&b2;
#pragma unroll
        for (int k = 0; k < 4; ++k) {
            const float w  = wp[k];
            const float X0 = p0[k], X1 = p1[k], X2 = p2[k];
            const float Y0 = X0 + q0[k], Y1 = X1 + q1[k], Y2 = X2 + q2[k];
            const float wX0 = w * X0, wX1 = w * X1, wX2 = w * X2;
            s[0]  += w;
            s[1]  += wX0;      s[2]  += wX1;      s[3]  += wX2;
            s[4]  += w * Y0;   s[5]  += w * Y1;   s[6]  += w * Y2;
            s[7]  += wX0 * Y0; s[8]  += wX0 * Y1; s[9]  += wX0 * Y2;
            s[10] += wX1 * Y0; s[11] += wX1 * Y1; s[12] += wX1 * Y2;
            s[13] += wX2 * Y0; s[14] += wX2 * Y1; s[15] += wX2 * Y2;
        }

        if (c + 1 < CHUNKS) {
            wv = nwv;
            a0 = na0; a1 = na1; a2 = na2;
            b0 = nb0; b1 = nb1; b2 = nb2;
        }
    }

    // wave (64-lane) butterfly reduce
#pragma unroll
    for (int off = 32; off > 0; off >>= 1) {
#pragma unroll
        for (int k = 0; k < 16; ++k) s[k] += __shfl_down(s[k], off, 64);
    }

    __shared__ float lds[TPB / 64][16];
    const int wave = threadIdx.x >> 6;
    const int lane = threadIdx.x & 63;
    if (lane == 0) {
#pragma unroll
        for (int k = 0; k < 16; ++k) lds[wave][k] = s[k];
    }
    __syncthreads();

    if (threadIdx.x != 0) return;   // waves 1..7 exit; wave 0 lanes 1..63 exit

    // ---- per-batch 3x3 Kabsch solve, f32 (threshold 2e-2; ample headroom) ----
    float S[16];
#pragma unroll
    for (int k = 0; k < 16; ++k) {
        float acc = 0.f;
#pragma unroll
        for (int wv2 = 0; wv2 < TPB / 64; ++wv2) acc += lds[wv2][k];
        S[k] = acc;
    }

    const float EPS = 1e-4f;
    const float Sw = S[0];
    float Sx[3] = {S[1], S[2], S[3]};
    float Sy[3] = {S[4], S[5], S[6]};

    const float sum_w = Sw + EPS;                 // sum(weights) + EPS
    const float denom = Sw / sum_w + EPS;         // sum(nw) + EPS
    const float mscale = 1.0f / (sum_w * denom);
    float mx[3], my[3];
#pragma unroll
    for (int i = 0; i < 3; ++i) { mx[i] = Sx[i] * mscale; my[i] = Sy[i] * mscale; }

    float H[3][3];
#pragma unroll
    for (int i = 0; i < 3; ++i)
#pragma unroll
        for (int j = 0; j < 3; ++j) {
            const float Sxy = S[7 + 3 * i + j];
            H[i][j] = (Sxy - mx[i] * Sy[j] - my[j] * Sx[i] + mx[i] * my[j] * Sw) / sum_w;
        }

    // A = H^T H (symmetric PSD)
    float A[3][3];
#pragma unroll
    for (int i = 0; i < 3; ++i)
#pragma unroll
        for (int j = 0; j < 3; ++j)
            A[i][j] = H[0][i] * H[0][j] + H[1][i] * H[1][j] + H[2][i] * H[2][j];

    float V[3][3] = {{1, 0, 0}, {0, 1, 0}, {0, 0, 1}};

    // cyclic Jacobi, 6 sweeps x 3 pivots — converged well past f32 eps for 3x3
    for (int sweep = 0; sweep < 6; ++sweep) {
        const int PP[3] = {0, 0, 1}, QQ[3] = {1, 2, 2};
#pragma unroll
        for (int r = 0; r < 3; ++r) {
            const int p = PP[r], q = QQ[r];
            const float apq = A[p][q];
            if (fabsf(apq) < 1e-30f) continue;
            const float theta = (A[q][q] - A[p][p]) / (2.0f * apq);
            const float t = copysignf(1.0f, theta) / (fabsf(theta) + sqrtf(1.0f + theta * theta));
            const float c = 1.0f / sqrtf(1.0f + t * t);
            const float sn = t * c;
            A[p][p] = A[p][p] - t * apq;
            A[q][q] = A[q][q] + t * apq;
            A[p][q] = A[q][p] = 0.0f;
            const int k = 3 - p - q;  // remaining index
            const float Akp = A[k][p], Akq = A[k][q];
            A[k][p] = A[p][k] = c * Akp - sn * Akq;
            A[k][q] = A[q][k] = sn * Akp + c * Akq;
#pragma unroll
            for (int m = 0; m < 3; ++m) {
                const float Vmp = V[m][p], Vmq = V[m][q];
                V[m][p] = c * Vmp - sn * Vmq;
                V[m][q] = sn * Vmp + c * Vmq;
            }
        }
    }

    // sort eigenpairs descending
    float ev[3] = {A[0][0], A[1][1], A[2][2]};
    int ord[3] = {0, 1, 2};
    if (ev[ord[0]] < ev[ord[1]]) { int tmp = ord[0]; ord[0] = ord[1]; ord[1] = tmp; }
    if (ev[ord[0]] < ev[ord[2]]) { int tmp = ord[0]; ord[0] = ord[2]; ord[2] = tmp; }
    if (ev[ord[1]] < ev[ord[2]]) { int tmp = ord[1]; ord[1] = ord[2]; ord[2] = tmp; }

    float Vs[3][3], Us[3][3], sig[3];
#pragma unroll
    for (int k = 0; k < 3; ++k) {
        const int c0 = ord[k];
        for (int m = 0; m < 3; ++m) Vs[m][k] = V[m][c0];
        float u0 = H[0][0] * Vs[0][k] + H[0][1] * Vs[1][k] + H[0][2] * Vs[2][k];
        float u1 = H[1][0] * Vs[0][k] + H[1][1] * Vs[1][k] + H[1][2] * Vs[2][k];
        float u2 = H[2][0] * Vs[0][k] + H[2][1] * Vs[1][k] + H[2][2] * Vs[2][k];
        const float nrm = sqrtf(u0 * u0 + u1 * u1 + u2 * u2);
        sig[k] = nrm;
        const float inv = (nrm > 1e-30f) ? 1.0f / nrm : 0.0f;
        Us[0][k] = u0 * inv; Us[1][k] = u1 * inv; Us[2][k] = u2 * inv;
    }
    // rank-2 safeguard: rebuild u3 orthogonal to u1,u2
    if (sig[2] <= 1e-6f * fmaxf(sig[0], 1e-30f)) {
        float c0 = Us[1][0] * Us[2][1] - Us[2][0] * Us[1][1];
        float c1 = Us[2][0] * Us[0][1] - Us[0][0] * Us[2][1];
        float c2 = Us[0][0] * Us[1][1] - Us[1][0] * Us[0][1];
        const float n = sqrtf(c0 * c0 + c1 * c1 + c2 * c2);
        const float inv = (n > 1e-30f) ? 1.0f / n : 0.0f;
        Us[0][2] = c0 * inv; Us[1][2] = c1 * inv; Us[2][2] = c2 * inv;
    }

    auto det3 = [](float M[3][3]) {
        return M[0][0] * (M[1][1] * M[2][2] - M[1][2] * M[2][1])
             - M[0][1] * (M[1][0] * M[2][2] - M[1][2] * M[2][0])
             + M[0][2] * (M[1][0] * M[2][1] - M[1][1] * M[2][0]);
    };
    const float d = (det3(Us) * det3(Vs) < 0.0f) ? -1.0f : 1.0f;

    // R = V diag(1,1,d) U^T ; t = my - R mx
    float R[3][3];
#pragma unroll
    for (int i = 0; i < 3; ++i)
#pragma unroll
        for (int j = 0; j < 3; ++j)
            R[i][j] = Vs[i][0] * Us[j][0] + Vs[i][1] * Us[j][1] + d * Vs[i][2] * Us[j][2];

    float* outR = out + (size_t)b * 9;
    float* outT = out + (size_t)B * 9 + (size_t)b * 3;
#pragma unroll
    for (int i = 0; i < 3; ++i) {
#pragma unroll
        for (int j = 0; j < 3; ++j) outR[i * 3 + j] = R[i][j];
        outT[i] = my[i] - (R[i][0] * mx[0] + R[i][1] * mx[1] + R[i][2] * mx[2]);
    }
}

extern "C" void kernel_launch(void* const* d_in, const int* in_sizes, int n_in,
                              void* d_out, int out_size, void* d_ws, size_t ws_size,
                              hipStream_t stream) {
    const float* src = (const float*)d_in[0];
    const float* rcs = (const float*)d_in[1];
    const float* wts = (const float*)d_in[2];
    float* out = (float*)d_out;

    const int B = in_sizes[2] / N_ELEM;  // 1024

    gw_fused_kernel<<<B, TPB, 0, stream>>>(src, rcs, wts, out, B);
}

// Round 5
// 46.053 us; speedup vs baseline: 1.1462x; 1.1462x over previous
//
#include <hip/hip_runtime.h>
#include <math.h>

// Problem geometry (from reference setup_inputs): B=1024, N=8192.
constexpr int N_ELEM = 8192;
constexpr int TPB    = 512;                 // threads per block (8 waves)
constexpr int CHUNKS = N_ELEM / 4 / TPB;    // float4 chunks per thread = 4

// ---------------------------------------------------------------------------
// Fused kernel: per-batch raw-moment reduction + 3x3 Kabsch solve.
// Sums (16 per batch):
//   s0      = sum w
//   s1..s3  = sum w * src_i
//   s4..s6  = sum w * (src_i + rcs_i)           (= corres)
//   s7..s15 = sum w * src_i * corres_j          (3x3, row-major)
// Then thread 0: cov -> SVD (f32 Jacobi on H^T H) -> R, t.
//
// TUNING LEDGER (do not re-try):
//  - R2: __launch_bounds__(512,8) forced VGPR=32 -> accumulators spilled to
//    scratch (WRITE 64 KB -> 210 MB), 48.8 -> 115 us. Plain bound only.
//  - R4: manual 2-deep prefetch pipeline -> VGPR 64 -> 68, crossed the
//    4-blocks/CU residency boundary (occupancy 28% -> 21%), 46.3 -> 52.8 us.
//    The kernel is DRAM/fabric-bound; extra per-wave ILP cannot pay for any
//    occupancy loss. Keep VGPR <= 64 (8 waves/SIMD, grid fully resident).
// ---------------------------------------------------------------------------
__global__ __launch_bounds__(TPB) void gw_fused_kernel(
    const float* __restrict__ src, const float* __restrict__ rcs,
    const float* __restrict__ wts, float* __restrict__ out, int B)
{
    const size_t b = blockIdx.x;
    const float4* w4 = (const float4*)(wts + b * (size_t)N_ELEM);
    const float4* x0 = (const float4*)(src + b * (size_t)(3 * N_ELEM));
    const float4* x1 = x0 + N_ELEM / 4;
    const float4* x2 = x0 + 2 * (N_ELEM / 4);
    const float4* r0 = (const float4*)(rcs + b * (size_t)(3 * N_ELEM));
    const float4* r1 = r0 + N_ELEM / 4;
    const float4* r2 = r0 + 2 * (N_ELEM / 4);

    float s[16];
#pragma unroll
    for (int k = 0; k < 16; ++k) s[k] = 0.f;

#pragma unroll
    for (int c = 0; c < CHUNKS; ++c) {
        const int idx = c * TPB + threadIdx.x;
        float4 wv = w4[idx];
        float4 a0 = x0[idx], a1 = x1[idx], a2 = x2[idx];
        float4 b0 = r0[idx], b1 = r1[idx], b2 = r2[idx];
        const float* wp = (const float*)&wv;
        const float* p0 = (const float*)&a0;
        const float* p1 = (const float*)&a1;
        const float* p2 = (const float*)&a2;
        const float* q0 = (const float*)&b0;
        const float* q1 = (const float*)&b1;
        const float* q2 = (const float*)&b2;
#pragma unroll
        for (int k = 0; k < 4; ++k) {
            const float w  = wp[k];
            const float X0 = p0[k], X1 = p1[k], X2 = p2[k];
            const float Y0 = X0 + q0[k], Y1 = X1 + q1[k], Y2 = X2 + q2[k];
            const float wX0 = w * X0, wX1 = w * X1, wX2 = w * X2;
            s[0]  += w;
            s[1]  += wX0;      s[2]  += wX1;      s[3]  += wX2;
            s[4]  += w * Y0;   s[5]  += w * Y1;   s[6]  += w * Y2;
            s[7]  += wX0 * Y0; s[8]  += wX0 * Y1; s[9]  += wX0 * Y2;
            s[10] += wX1 * Y0; s[11] += wX1 * Y1; s[12] += wX1 * Y2;
            s[13] += wX2 * Y0; s[14] += wX2 * Y1; s[15] += wX2 * Y2;
        }
    }

    // wave (64-lane) butterfly reduce
#pragma unroll
    for (int off = 32; off > 0; off >>= 1) {
#pragma unroll
        for (int k = 0; k < 16; ++k) s[k] += __shfl_down(s[k], off, 64);
    }

    __shared__ float lds[TPB / 64][16];
    const int wave = threadIdx.x >> 6;
    const int lane = threadIdx.x & 63;
    if (lane == 0) {
#pragma unroll
        for (int k = 0; k < 16; ++k) lds[wave][k] = s[k];
    }
    __syncthreads();

    if (threadIdx.x != 0) return;   // waves 1..7 exit; wave 0 lanes 1..63 exit

    // ---- per-batch 3x3 Kabsch solve, f32 (threshold 2e-2; ample headroom) ----
    float S[16];
#pragma unroll
    for (int k = 0; k < 16; ++k) {
        float acc = 0.f;
#pragma unroll
        for (int wv = 0; wv < TPB / 64; ++wv) acc += lds[wv][k];
        S[k] = acc;
    }

    const float EPS = 1e-4f;
    const float Sw = S[0];
    float Sx[3] = {S[1], S[2], S[3]};
    float Sy[3] = {S[4], S[5], S[6]};

    const float sum_w = Sw + EPS;                 // sum(weights) + EPS
    const float denom = Sw / sum_w + EPS;         // sum(nw) + EPS
    const float mscale = 1.0f / (sum_w * denom);
    float mx[3], my[3];
#pragma unroll
    for (int i = 0; i < 3; ++i) { mx[i] = Sx[i] * mscale; my[i] = Sy[i] * mscale; }

    float H[3][3];
#pragma unroll
    for (int i = 0; i < 3; ++i)
#pragma unroll
        for (int j = 0; j < 3; ++j) {
            const float Sxy = S[7 + 3 * i + j];
            H[i][j] = (Sxy - mx[i] * Sy[j] - my[j] * Sx[i] + mx[i] * my[j] * Sw) / sum_w;
        }

    // A = H^T H (symmetric PSD)
    float A[3][3];
#pragma unroll
    for (int i = 0; i < 3; ++i)
#pragma unroll
        for (int j = 0; j < 3; ++j)
            A[i][j] = H[0][i] * H[0][j] + H[1][i] * H[1][j] + H[2][i] * H[2][j];

    float V[3][3] = {{1, 0, 0}, {0, 1, 0}, {0, 0, 1}};

    // cyclic Jacobi, 6 sweeps x 3 pivots — converged well past f32 eps for 3x3
    for (int sweep = 0; sweep < 6; ++sweep) {
        const int PP[3] = {0, 0, 1}, QQ[3] = {1, 2, 2};
#pragma unroll
        for (int r = 0; r < 3; ++r) {
            const int p = PP[r], q = QQ[r];
            const float apq = A[p][q];
            if (fabsf(apq) < 1e-30f) continue;
            const float theta = (A[q][q] - A[p][p]) / (2.0f * apq);
            const float t = copysignf(1.0f, theta) / (fabsf(theta) + sqrtf(1.0f + theta * theta));
            const float c = 1.0f / sqrtf(1.0f + t * t);
            const float sn = t * c;
            A[p][p] = A[p][p] - t * apq;
            A[q][q] = A[q][q] + t * apq;
            A[p][q] = A[q][p] = 0.0f;
            const int k = 3 - p - q;  // remaining index
            const float Akp = A[k][p], Akq = A[k][q];
            A[k][p] = A[p][k] = c * Akp - sn * Akq;
            A[k][q] = A[q][k] = sn * Akp + c * Akq;
#pragma unroll
            for (int m = 0; m < 3; ++m) {
                const float Vmp = V[m][p], Vmq = V[m][q];
                V[m][p] = c * Vmp - sn * Vmq;
                V[m][q] = sn * Vmp + c * Vmq;
            }
        }
    }

    // sort eigenpairs descending
    float ev[3] = {A[0][0], A[1][1], A[2][2]};
    int ord[3] = {0, 1, 2};
    if (ev[ord[0]] < ev[ord[1]]) { int tmp = ord[0]; ord[0] = ord[1]; ord[1] = tmp; }
    if (ev[ord[0]] < ev[ord[2]]) { int tmp = ord[0]; ord[0] = ord[2]; ord[2] = tmp; }
    if (ev[ord[1]] < ev[ord[2]]) { int tmp = ord[1]; ord[1] = ord[2]; ord[2] = tmp; }

    float Vs[3][3], Us[3][3], sig[3];
#pragma unroll
    for (int k = 0; k < 3; ++k) {
        const int c0 = ord[k];
        for (int m = 0; m < 3; ++m) Vs[m][k] = V[m][c0];
        float u0 = H[0][0] * Vs[0][k] + H[0][1] * Vs[1][k] + H[0][2] * Vs[2][k];
        float u1 = H[1][0] * Vs[0][k] + H[1][1] * Vs[1][k] + H[1][2] * Vs[2][k];
        float u2 = H[2][0] * Vs[0][k] + H[2][1] * Vs[1][k] + H[2][2] * Vs[2][k];
        const float nrm = sqrtf(u0 * u0 + u1 * u1 + u2 * u2);
        sig[k] = nrm;
        const float inv = (nrm > 1e-30f) ? 1.0f / nrm : 0.0f;
        Us[0][k] = u0 * inv; Us[1][k] = u1 * inv; Us[2][k] = u2 * inv;
    }
    // rank-2 safeguard: rebuild u3 orthogonal to u1,u2
    if (sig[2] <= 1e-6f * fmaxf(sig[0], 1e-30f)) {
        float c0 = Us[1][0] * Us[2][1] - Us[2][0] * Us[1][1];
        float c1 = Us[2][0] * Us[0][1] - Us[0][0] * Us[2][1];
        float c2 = Us[0][0] * Us[1][1] - Us[1][0] * Us[0][1];
        const float n = sqrtf(c0 * c0 + c1 * c1 + c2 * c2);
        const float inv = (n > 1e-30f) ? 1.0f / n : 0.0f;
        Us[0][2] = c0 * inv; Us[1][2] = c1 * inv; Us[2][2] = c2 * inv;
    }

    auto det3 = [](float M[3][3]) {
        return M[0][0] * (M[1][1] * M[2][2] - M[1][2] * M[2][1])
             - M[0][1] * (M[1][0] * M[2][2] - M[1][2] * M[2][0])
             + M[0][2] * (M[1][0] * M[2][1] - M[1][1] * M[2][0]);
    };
    const float d = (det3(Us) * det3(Vs) < 0.0f) ? -1.0f : 1.0f;

    // R = V diag(1,1,d) U^T ; t = my - R mx
    float R[3][3];
#pragma unroll
    for (int i = 0; i < 3; ++i)
#pragma unroll
        for (int j = 0; j < 3; ++j)
            R[i][j] = Vs[i][0] * Us[j][0] + Vs[i][1] * Us[j][1] + d * Vs[i][2] * Us[j][2];

    float* outR = out + (size_t)b * 9;
    float* outT = out + (size_t)B * 9 + (size_t)b * 3;
#pragma unroll
    for (int i = 0; i < 3; ++i) {
#pragma unroll
        for (int j = 0; j < 3; ++j) outR[i * 3 + j] = R[i][j];
        outT[i] = my[i] - (R[i][0] * mx[0] + R[i][1] * mx[1] + R[i][2] * mx[2]);
    }
}

extern "C" void kernel_launch(void* const* d_in, const int* in_sizes, int n_in,
                              void* d_out, int out_size, void* d_ws, size_t ws_size,
                              hipStream_t stream) {
    const float* src = (const float*)d_in[0];
    const float* rcs = (const float*)d_in[1];
    const float* wts = (const float*)d_in[2];
    float* out = (float*)d_out;

    const int B = in_sizes[2] / N_ELEM;  // 1024

    gw_fused_kernel<<<B, TPB, 0, stream>>>(src, rcs, wts, out, B);
}